// Round 2
// baseline (288.142 us; speedup 1.0000x reference)
//
#include <hip/hip_runtime.h>

// HierarchicalGraphSAGE bf16-MFMA version, R20.
// N=50000, E=800000, D=128, OUT=64, G=64.
//
//  R20 vs R19:
//   - k_tail's edge graph-sum REPLACED by histogram + MFMA GEMM:
//     gsumE[g][f] = sum_s cnt[g][s] * h2[s][f]. cnt built early (folded
//     into k_bincast; depends only on edges+batch). Layer-2 epilogue also
//     writes transposed fp8 h2T[f][s] so the GEMM B-operand is
//     k-contiguous. Kills the third 800K x 128B random gather (~40us ->
//     ~8us). Counts<=16 and fp8 values are exact in bf16; f32 accum.
//   - k_layer: 256-thr blocks (16 nodes, 4-wave sync domain), csr index
//     chunks for all 4 nodes prefetched up-front (4 independent chains),
//     f32x2 packed accumulators (v_pk_add_f32) in the fp8 decode loop.

typedef __bf16 bf16x8 __attribute__((ext_vector_type(8)));
typedef float f32x4 __attribute__((ext_vector_type(4)));
typedef float f32x2 __attribute__((ext_vector_type(2)));

#define BINB 160
#define NBMAX 512

static __device__ __forceinline__ unsigned short f2bf(float f) {
    unsigned u = __builtin_bit_cast(unsigned, f);
    return (unsigned short)((u + 0x7fffu + ((u >> 16) & 1u)) >> 16);
}
static __device__ __forceinline__ uint2 pk8_fp8(const float* f) {
    int lo = 0, hi = 0;
    lo = __builtin_amdgcn_cvt_pk_fp8_f32(f[0], f[1], lo, false);
    lo = __builtin_amdgcn_cvt_pk_fp8_f32(f[2], f[3], lo, true);
    hi = __builtin_amdgcn_cvt_pk_fp8_f32(f[4], f[5], hi, false);
    hi = __builtin_amdgcn_cvt_pk_fp8_f32(f[6], f[7], hi, true);
    return make_uint2((unsigned)lo, (unsigned)hi);
}
static __device__ __forceinline__ unsigned char f2fp8(float v) {
    return (unsigned char)(__builtin_amdgcn_cvt_pk_fp8_f32(v, v, 0, false) & 0xff);
}

// ---------------- bucket count + cast + weight pack + edge histogram -------
// blocks [0, BINB)                 : dst bincount
// blocks [BINB, +nxblk)            : x -> bf16 frags + fp8 rows
// blocks [BINB+nxblk, +256)        : weight frag pack (2 layers)
// blocks [BINB+nxblk+256, +HISTB)  : cnt[g][s] += 1 per edge s->g
__global__ __launch_bounds__(256) void k_bincast(
    const int* __restrict__ ei, int* __restrict__ cnt_mat, int E, int nb, int epb,
    const float* __restrict__ x, unsigned short* __restrict__ xb,
    unsigned char* __restrict__ x8, int n8, int nxblk,
    const float* __restrict__ W1l, const float* __restrict__ W1r,
    const float* __restrict__ W2l, const float* __restrict__ W2r,
    unsigned short* __restrict__ Whi,
    const int* __restrict__ batch, unsigned* __restrict__ cnt, int nsp, int hepb)
{
    __shared__ int lc[NBMAX];
    int bid = blockIdx.x;
    if (bid < BINB) {
        for (int i = threadIdx.x; i < nb; i += 256) lc[i] = 0;
        __syncthreads();
        int b0 = bid * epb;
        int b1 = min(b0 + epb, E);
        for (int i = b0 + threadIdx.x; i < b1; i += 256)
            atomicAdd(&lc[ei[E + i] >> 7], 1);
        __syncthreads();
        for (int i = threadIdx.x; i < nb; i += 256)
            cnt_mat[i * BINB + bid] = lc[i];
    } else if (bid < BINB + nxblk) {
        int i = (bid - BINB) * 256 + threadIdx.x;
        if (i >= n8) return;
        float f[8];
        *(float4*)(f + 0) = *(const float4*)(x + (size_t)i * 8);
        *(float4*)(f + 4) = *(const float4*)(x + (size_t)i * 8 + 4);
        ushort4 oa, ob;
        oa.x = f2bf(f[0]); oa.y = f2bf(f[1]); oa.z = f2bf(f[2]); oa.w = f2bf(f[3]);
        ob.x = f2bf(f[4]); ob.y = f2bf(f[5]); ob.z = f2bf(f[6]); ob.w = f2bf(f[7]);
        int node = i >> 4, c = i & 15;
        size_t dstb = (size_t)(node >> 4) * 2048 + (size_t)(c >> 2) * 512
                    + (size_t)((c & 3) * 16 + (node & 15)) * 8;
        *(ushort4*)(xb + dstb) = oa;
        *(ushort4*)(xb + dstb + 4) = ob;
        *(uint2*)(x8 + (size_t)i * 8) = pk8_fp8(f);
    } else if (bid < BINB + nxblk + 256) {
        int wb = bid - BINB - nxblk;   // 0..255 (2 layers)
        int layer = wb >> 7;
        int j = wb & 127;
        int k = threadIdx.x;
        const float* Wl = (layer == 0) ? W1l : W2l;
        const float* Wr = (layer == 0) ? W1r : W2r;
        float w = (k < 128) ? Wl[j * 128 + k] : Wr[j * 128 + k - 128];
        int js = j >> 4, mr = j & 15;
        int s = k >> 5, quad = (k >> 3) & 3, e = k & 7;
        size_t o = (size_t)layer * 32768
                 + ((size_t)(js * 8 + s) * 64 + quad * 16 + mr) * 8 + e;
        Whi[o] = f2bf(w);
    } else {
        int hb = bid - BINB - nxblk - 256;
        int b0 = hb * hepb;
        int b1 = min(b0 + hepb, E);
        for (int i = b0 + threadIdx.x; i < b1; i += 256) {
            int s = ei[i];
            int d = ei[E + i];
            int g = batch[d];
            atomicAdd(&cnt[(size_t)g * nsp + s], 1u);
        }
    }
}

__global__ __launch_bounds__(256) void k_mrowscan(
    const int* __restrict__ cnt_mat, int* __restrict__ rowloc, int* __restrict__ btot)
{
    __shared__ int s[256];
    int b = blockIdx.x;
    int t = threadIdx.x;
    int v = (t < BINB) ? cnt_mat[b * BINB + t] : 0;
    s[t] = v;
    __syncthreads();
#pragma unroll
    for (int off = 1; off < 256; off <<= 1) {
        int u = (t >= off) ? s[t - off] : 0;
        __syncthreads();
        s[t] += u;
        __syncthreads();
    }
    if (t < BINB) rowloc[b * BINB + t] = s[t] - v;
    if (t == 255) btot[b] = s[255];
}

__global__ __launch_bounds__(256) void k_scan2b(
    const int* __restrict__ btot, int* __restrict__ bbase, int nb, int* __restrict__ total_out)
{
    __shared__ int s[256];
    int t = threadIdx.x;
    int per = (nb + 255) / 256;
    int s0 = t * per, e0 = min(s0 + per, nb);
    int sum = 0;
    for (int i = s0; i < e0; ++i) sum += btot[i];
    s[t] = sum;
    __syncthreads();
#pragma unroll
    for (int off = 1; off < 256; off <<= 1) {
        int u = (t >= off) ? s[t - off] : 0;
        __syncthreads();
        s[t] += u;
        __syncthreads();
    }
    int run = s[t] - sum;
    for (int i = s0; i < e0; ++i) { bbase[i] = run; run += btot[i]; }
    if (t == 255) *total_out = s[255];
}

__global__ __launch_bounds__(256) void k_binscatter(
    const int* __restrict__ ei, const int* __restrict__ rowloc, const int* __restrict__ bbase,
    unsigned* __restrict__ binned, int E, int nb, int epb)
{
    __shared__ int lofs[NBMAX];
    __shared__ int lcnt[NBMAX];
    for (int i = threadIdx.x; i < nb; i += 256) {
        lofs[i] = rowloc[i * BINB + blockIdx.x] + bbase[i];
        lcnt[i] = 0;
    }
    __syncthreads();
    int b0 = blockIdx.x * epb;
    int b1 = min(b0 + epb, E);
    for (int i = b0 + threadIdx.x; i < b1; i += 256) {
        int s = ei[i];
        int d = ei[E + i];
        int b = d >> 7;
        int r = atomicAdd(&lcnt[b], 1);
        binned[lofs[b] + r] = (unsigned)s | ((unsigned)(d & 127) << 16);
    }
}

// Per-bucket fine stage + gestart fold (kept; negligible cost).
__global__ __launch_bounds__(256) void k_fillfine2(
    const unsigned* __restrict__ binned, const int* __restrict__ bbase,
    const int* __restrict__ batch, int* __restrict__ starts,
    unsigned short* __restrict__ csr_src, int* __restrict__ gestart,
    int E, int nb, int n)
{
    __shared__ int lc[128];
    __shared__ int lpos[128];
    int b = blockIdx.x;
    int t = threadIdx.x;
    int node0 = b << 7;
    int bs = bbase[b];
    int be = (b == nb - 1) ? E : bbase[b + 1];
    if (t < 128) lc[t] = 0;
    __syncthreads();
    for (int i = bs + t; i < be; i += 256)
        atomicAdd(&lc[(binned[i] >> 16) & 127], 1);
    __syncthreads();
    int v = (t < 128) ? lc[t] : 0;
    if (t < 128) lpos[t] = v;
    __syncthreads();
#pragma unroll
    for (int off = 1; off < 128; off <<= 1) {
        int u = (t >= off && t < 128) ? lpos[t - off] : 0;
        __syncthreads();
        if (t < 128) lpos[t] += u;
        __syncthreads();
    }
    int excl = (t < 128) ? (lpos[t] - v) : 0;
    __syncthreads();
    if (t < 128) {
        int node = node0 + t;
        if (node < n) {
            int st = bs + excl;
            starts[node] = st;
            int bc = batch[node];
            int bp = (node == 0) ? -1 : batch[node - 1];
            for (int g = bp + 1; g <= bc; ++g) gestart[g] = st;
            if (node == n - 1)
                for (int g = bc + 1; g <= 64; ++g) gestart[g] = E;
        }
        lpos[t] = bs + excl;
    }
    if (b == nb - 1 && t == 0) starts[n] = E;
    __syncthreads();
    for (int i = bs + t; i < be; i += 256) {
        unsigned e = binned[i];
        int slot = atomicAdd(&lpos[(e >> 16) & 127], 1);
        csr_src[slot] = (unsigned short)(e & 0xffffu);
    }
}

// ---------------- shared gather helpers (f32x2 packed accumulators) --------
#define ACC8P(v)                                                        \
    do {                                                                \
        f32x2 p0 = __builtin_amdgcn_cvt_pk_f32_fp8((v).x, false);       \
        f32x2 p1 = __builtin_amdgcn_cvt_pk_f32_fp8((v).x, true);        \
        f32x2 p2 = __builtin_amdgcn_cvt_pk_f32_fp8((v).y, false);       \
        f32x2 p3 = __builtin_amdgcn_cvt_pk_f32_fp8((v).y, true);        \
        A01 += p0; A23 += p1; A45 += p2; A67 += p3;                     \
    } while (0)

#define PROC_CHUNK(idxv, cntv)                                          \
    {                                                                   \
        int j = 0;                                                      \
        for (; j + 16 <= (cntv); j += 16) {                             \
            int s0 = __shfl((int)(idxv), j + eg);                       \
            int s1 = __shfl((int)(idxv), j + 4 + eg);                   \
            int s2 = __shfl((int)(idxv), j + 8 + eg);                   \
            int s3 = __shfl((int)(idxv), j + 12 + eg);                  \
            uint2 v0 = *(const uint2*)(hrow + (size_t)s0 * 128);        \
            uint2 v1 = *(const uint2*)(hrow + (size_t)s1 * 128);        \
            uint2 v2 = *(const uint2*)(hrow + (size_t)s2 * 128);        \
            uint2 v3 = *(const uint2*)(hrow + (size_t)s3 * 128);        \
            ACC8P(v0);                                                  \
            ACC8P(v1);                                                  \
            ACC8P(v2);                                                  \
            ACC8P(v3);                                                  \
        }                                                               \
        for (; j + 4 <= (cntv); j += 4) {                               \
            int s0 = __shfl((int)(idxv), j + eg);                       \
            uint2 v0 = *(const uint2*)(hrow + (size_t)s0 * 128);        \
            ACC8P(v0);                                                  \
        }                                                               \
        if (j < (cntv)) {                                               \
            int k = j + eg;                                             \
            int sm = __shfl((int)(idxv), (k < (cntv)) ? k : ((cntv) - 1)); \
            uint2 v = *(const uint2*)(hrow + (size_t)sm * 128);         \
            if (k >= (cntv)) v = make_uint2(0u, 0u);                    \
            ACC8P(v);                                                   \
        }                                                               \
    }

#define REDUCE8()                                                       \
    a0 += __shfl_xor(a0, 16); a0 += __shfl_xor(a0, 32);                 \
    a1 += __shfl_xor(a1, 16); a1 += __shfl_xor(a1, 32);                 \
    a2 += __shfl_xor(a2, 16); a2 += __shfl_xor(a2, 32);                 \
    a3 += __shfl_xor(a3, 16); a3 += __shfl_xor(a3, 32);                 \
    a4 += __shfl_xor(a4, 16); a4 += __shfl_xor(a4, 32);                 \
    a5 += __shfl_xor(a5, 16); a5 += __shfl_xor(a5, 32);                 \
    a6 += __shfl_xor(a6, 16); a6 += __shfl_xor(a6, 32);                 \
    a7 += __shfl_xor(a7, 16); a7 += __shfl_xor(a7, 32);

// ---------------- fused SAGE layer: gather->LDS frags -> MFMA GEMM ---------
// 256 threads = 4 waves own 16 nodes. Phase 1: wave wv gathers nodes
// node0+wv*4..+3 with all 4 csr chunks prefetched. Phase 2: wave wv computes
// col-tiles js=2wv,2wv+1 for the 16 nodes; A s<4 from LDS, s>=4 from hf.
// Layer2 (do_h2t): epilogue also writes transposed fp8 h2T[col][node]
// (pad nodes [n, nsp) written as zeros by the extra pad block).
__global__ __launch_bounds__(256) void k_layer(
    const unsigned char* __restrict__ h8_in, const int* __restrict__ starts,
    const unsigned short* __restrict__ csr, const unsigned short* __restrict__ hf,
    const unsigned short* __restrict__ Whi, const float* __restrict__ bl,
    unsigned short* __restrict__ outf, unsigned char* __restrict__ out8,
    unsigned char* __restrict__ h2t,
    int n, int nsp, int do_outf, int do_h2t)
{
    __shared__ unsigned short sagg[2048];   // 16 nodes x 128 x bf16 = 4KB
    int t = threadIdx.x;
    int wv = t >> 6;
    int lane = t & 63;
    int node0 = blockIdx.x * 16;

    // ---- gather phase ----
    {
        int eg = lane >> 4;
        int fb = lane & 15;
        const unsigned char* hrow = h8_in + fb * 8;
        int nodeA = node0 + wv * 4;
        int st[5];
#pragma unroll
        for (int r = 0; r < 5; ++r) {
            int nn = nodeA + r;
            st[r] = starts[nn > n ? n : nn];
        }
        unsigned idx4[4];
#pragma unroll
        for (int r = 0; r < 4; ++r)
            idx4[r] = (st[r] + lane < st[r + 1]) ? (unsigned)csr[st[r] + lane] : 0u;

#pragma unroll
        for (int r = 0; r < 4; ++r) {
            int node = nodeA + r;
            if (node >= n) break;
            f32x2 A01 = (f32x2){0.f, 0.f}, A23 = (f32x2){0.f, 0.f},
                  A45 = (f32x2){0.f, 0.f}, A67 = (f32x2){0.f, 0.f};
            int deg = st[r + 1] - st[r];
            int c0 = min(64, deg);
            PROC_CHUNK(idx4[r], c0)
            for (int base = st[r] + 64; base < st[r + 1]; base += 64) {
                int cnt2 = min(64, st[r + 1] - base);
                unsigned idx = (base + lane < st[r + 1]) ? (unsigned)csr[base + lane] : 0u;
                PROC_CHUNK(idx, cnt2)
            }
            float a0 = A01.x, a1 = A01.y, a2 = A23.x, a3 = A23.y,
                  a4 = A45.x, a5 = A45.y, a6 = A67.x, a7 = A67.y;
            REDUCE8()
            if (eg == 0) {
                int ln = node - node0;   // 0..15
                unsigned u0 = (unsigned)f2bf(a0) | ((unsigned)f2bf(a1) << 16);
                unsigned u1 = (unsigned)f2bf(a2) | ((unsigned)f2bf(a3) << 16);
                unsigned u2 = (unsigned)f2bf(a4) | ((unsigned)f2bf(a5) << 16);
                unsigned u3 = (unsigned)f2bf(a6) | ((unsigned)f2bf(a7) << 16);
                size_t dst = (size_t)(fb >> 2) * 512 + (size_t)((fb & 3) * 16 + ln) * 8;
                *(uint4*)(sagg + dst) = make_uint4(u0, u1, u2, u3);
            }
        }
    }
    __syncthreads();

    // ---- GEMM phase ----
    int quad = lane >> 4;
    int mr = lane & 15;
    int js0 = wv * 2;

    f32x4 acc0 = (f32x4){0.f, 0.f, 0.f, 0.f};
    f32x4 acc1 = (f32x4){0.f, 0.f, 0.f, 0.f};

    const unsigned short* wp = Whi + (size_t)js0 * 4096 + (size_t)lane * 8;
    const unsigned short* sa = sagg + (size_t)lane * 8;
    const unsigned short* ha = hf + (size_t)blockIdx.x * 2048 + (size_t)lane * 8;

    uint4 pb[2][3];
#define LAYER_LOAD(s, b)                                                  \
    do {                                                                  \
        pb[b][0] = *(const uint4*)(wp + (size_t)(s) * 512);               \
        pb[b][1] = *(const uint4*)(wp + 4096 + (size_t)(s) * 512);        \
        pb[b][2] = ((s) < 4)                                              \
            ? *(const uint4*)(sa + (size_t)(s) * 512)                     \
            : *(const uint4*)(ha + (size_t)((s) - 4) * 512);              \
    } while (0)

    LAYER_LOAD(0, 0);
    LAYER_LOAD(1, 1);
#pragma unroll
    for (int s = 0; s < 8; ++s) {
        int b = s & 1;
        bf16x8 bh0 = __builtin_bit_cast(bf16x8, pb[b][0]);
        bf16x8 bh1 = __builtin_bit_cast(bf16x8, pb[b][1]);
        bf16x8 A0 = __builtin_bit_cast(bf16x8, pb[b][2]);
        acc0 = __builtin_amdgcn_mfma_f32_16x16x32_bf16(A0, bh0, acc0, 0, 0, 0);
        acc1 = __builtin_amdgcn_mfma_f32_16x16x32_bf16(A0, bh1, acc1, 0, 0, 0);
        if (s + 2 < 8) LAYER_LOAD(s + 2, b);
    }
#undef LAYER_LOAD

#pragma unroll
    for (int mi = 0; mi < 2; ++mi) {
        f32x4 a = mi ? acc1 : acc0;
        int col = (js0 + mi) * 16 + mr;
        float bias = bl[col];
        int q2 = (col >> 3) & 3;
        int e2 = col & 7;
        int so = col >> 5;
        float vr[4];
#pragma unroll
        for (int r = 0; r < 4; ++r) {
            int node = node0 + quad * 4 + r;
            float v = a[r] + bias;
            v = fmaxf(v, 0.f);
            vr[r] = (node < n) ? v : 0.f;
            if (node < n) {
                if (do_outf)
                    outf[(size_t)(node >> 4) * 2048 + (size_t)so * 512
                         + (size_t)(q2 * 16 + (node & 15)) * 8 + e2] = f2bf(v);
                out8[(size_t)node * 128 + col] = f2fp8(v);
            }
        }
        if (do_h2t) {
            int pk = __builtin_amdgcn_cvt_pk_fp8_f32(vr[0], vr[1], 0, false);
            pk = __builtin_amdgcn_cvt_pk_fp8_f32(vr[2], vr[3], pk, true);
            *(unsigned*)(h2t + (size_t)col * nsp + node0 + quad * 4) = (unsigned)pk;
        }
    }
}

// ---------------- gsum: cnt x h2T MFMA GEMM (gsumE) + node pool (gsumP) ----
// blocks [0, gb)   : GEMM, K-split; wave wv owns g-tile wv, loops 8 f-tiles.
// blocks [gb, ...) : node-sum of h2 rows per graph (gsumP).
__global__ __launch_bounds__(256) void k_gsum(
    const unsigned* __restrict__ cnt, const unsigned char* __restrict__ h2t,
    const unsigned char* __restrict__ h8, const int* __restrict__ batch,
    float* __restrict__ gsumE, float* __restrict__ gsumP,
    int n, int nsp, int ksteps, int gb)
{
    int t = threadIdx.x;
    if ((int)blockIdx.x >= gb) {
        // ---- pool branch ----
        int wave = ((blockIdx.x - gb) * 256 + t) >> 6;
        int lane = t & 63;
        int r0 = wave * 16;
        if (r0 >= n) return;
        int r1 = min(r0 + 16, n);
        int cur = batch[r0];
        float ax = 0.f, ay = 0.f;
        for (int i = r0; i < r1; ++i) {
            int g = batch[i];
            uchar2 v = *(const uchar2*)(h8 + (size_t)i * 128 + lane * 2);
            if (g != cur) {
                atomicAdd(&gsumP[cur * 128 + lane * 2], ax);
                atomicAdd(&gsumP[cur * 128 + lane * 2 + 1], ay);
                ax = 0.f; ay = 0.f; cur = g;
            }
            unsigned pk = (unsigned)v.x | ((unsigned)v.y << 8);
            f32x2 p = __builtin_amdgcn_cvt_pk_f32_fp8((int)pk, false);
            ax += p.x;
            ay += p.y;
        }
        atomicAdd(&gsumP[cur * 128 + lane * 2], ax);
        atomicAdd(&gsumP[cur * 128 + lane * 2 + 1], ay);
        return;
    }

    // ---- GEMM branch ----
    int wv = t >> 6;
    int lane = t & 63;
    int fast = lane & 15;
    int kc = (lane >> 4) * 8;
    int kpb = (ksteps + gb - 1) / gb;
    int k0 = blockIdx.x * kpb, k1 = min(k0 + kpb, ksteps);
    if (k0 >= k1) return;

    f32x4 acc[8];
#pragma unroll
    for (int i = 0; i < 8; ++i) acc[i] = (f32x4){0.f, 0.f, 0.f, 0.f};

    const unsigned* ap = cnt + (size_t)(wv * 16 + fast) * nsp + kc;
    const unsigned char* bp = h2t + (size_t)fast * nsp + kc;

    for (int ks = k0; ks < k1; ++ks) {
        int kb = ks * 32;
        uint4 c0 = *(const uint4*)(ap + kb);
        uint4 c1 = *(const uint4*)(ap + kb + 4);
        unsigned q0 = (unsigned)f2bf((float)c0.x) | ((unsigned)f2bf((float)c0.y) << 16);
        unsigned q1 = (unsigned)f2bf((float)c0.z) | ((unsigned)f2bf((float)c0.w) << 16);
        unsigned q2 = (unsigned)f2bf((float)c1.x) | ((unsigned)f2bf((float)c1.y) << 16);
        unsigned q3 = (unsigned)f2bf((float)c1.z) | ((unsigned)f2bf((float)c1.w) << 16);
        uint4 au = make_uint4(q0, q1, q2, q3);
        bf16x8 af = __builtin_bit_cast(bf16x8, au);
#pragma unroll
        for (int ft = 0; ft < 8; ++ft) {
            uint2 bb = *(const uint2*)(bp + (size_t)ft * 16 * nsp + kb);
            f32x2 p0 = __builtin_amdgcn_cvt_pk_f32_fp8(bb.x, false);
            f32x2 p1 = __builtin_amdgcn_cvt_pk_f32_fp8(bb.x, true);
            f32x2 p2 = __builtin_amdgcn_cvt_pk_f32_fp8(bb.y, false);
            f32x2 p3 = __builtin_amdgcn_cvt_pk_f32_fp8(bb.y, true);
            unsigned b0 = (unsigned)f2bf(p0.x) | ((unsigned)f2bf(p0.y) << 16);
            unsigned b1 = (unsigned)f2bf(p1.x) | ((unsigned)f2bf(p1.y) << 16);
            unsigned b2 = (unsigned)f2bf(p2.x) | ((unsigned)f2bf(p2.y) << 16);
            unsigned b3 = (unsigned)f2bf(p3.x) | ((unsigned)f2bf(p3.y) << 16);
            uint4 bu = make_uint4(b0, b1, b2, b3);
            bf16x8 bf = __builtin_bit_cast(bf16x8, bu);
            acc[ft] = __builtin_amdgcn_mfma_f32_16x16x32_bf16(af, bf, acc[ft], 0, 0, 0);
        }
    }

    int quad = lane >> 4;
    int mr = lane & 15;
    int gg = wv * 16 + quad * 4;
#pragma unroll
    for (int ft = 0; ft < 8; ++ft) {
        int col = ft * 16 + mr;
#pragma unroll
        for (int r = 0; r < 4; ++r)
            atomicAdd(&gsumE[(size_t)(gg + r) * 128 + col], acc[ft][r]);
    }
}

// ---------------- final: collapsed layer 3 + mean + head, fp32 -------------
__global__ __launch_bounds__(128) void k_final(
    const float* __restrict__ gsumE, const float* __restrict__ gsumP,
    const int* __restrict__ batch,
    const float* __restrict__ W3l, const float* __restrict__ b3,
    const float* __restrict__ W3r,
    const float* __restrict__ Wlin, const float* __restrict__ blin,
    float* __restrict__ out, int n)
{
    __shared__ float tmp[128];
    int g = blockIdx.x;   // 64
    int t = threadIdx.x;  // 128
    int lo = 0, hi = n;
    while (lo < hi) { int m = (lo + hi) >> 1; if (batch[m] < g) lo = m + 1; else hi = m; }
    int lb = lo;
    hi = n;
    while (lo < hi) { int m = (lo + hi) >> 1; if (batch[m] < g + 1) lo = m + 1; else hi = m; }
    int cnt = lo - lb;
    float inv = (cnt > 0) ? 1.f / (float)cnt : 0.f;

    float acc = 0.f;
    for (int k = 0; k < 128; ++k)
        acc += gsumE[g * 128 + k] * W3l[t * 128 + k]
             + gsumP[g * 128 + k] * W3r[t * 128 + k];
    tmp[t] = acc * inv + ((cnt > 0) ? b3[t] : 0.f);
    __syncthreads();

    if (t < 64) {
        float o = 0.f;
        for (int k = 0; k < 128; ++k)
            o += tmp[k] * Wlin[t * 128 + k];
        out[g * 64 + t] = o + blin[t];
    }
}

extern "C" void kernel_launch(void* const* d_in, const int* in_sizes, int n_in,
                              void* d_out, int out_size, void* d_ws, size_t ws_size,
                              hipStream_t stream) {
    const float* x     = (const float*)d_in[0];
    const int*   ei    = (const int*)d_in[1];
    const int*   batch = (const int*)d_in[2];
    const float* W1l = (const float*)d_in[3];
    const float* b1l = (const float*)d_in[4];
    const float* W1r = (const float*)d_in[5];
    const float* W2l = (const float*)d_in[6];
    const float* b2l = (const float*)d_in[7];
    const float* W2r = (const float*)d_in[8];
    const float* W3l = (const float*)d_in[9];
    const float* b3l = (const float*)d_in[10];
    const float* W3r = (const float*)d_in[11];
    const float* Wlin = (const float*)d_in[12];
    const float* blin = (const float*)d_in[13];

    const int N = in_sizes[2];       // 50000
    const int E = in_sizes[1] / 2;   // 800000
    const int nb = (N + 127) >> 7;   // 391 buckets
    const int epb = (E + BINB - 1) / BINB;
    const int NSP = ((N + 16 + 31) / 32) * 32;   // 50016 (pad, mult of 32)
    const int KSTEPS = NSP / 32;                  // 1563

    size_t off = 0;
    auto alloc = [&](size_t bytes) {
        void* p = (char*)d_ws + off;
        off += (bytes + 255) & ~(size_t)255;
        return p;
    };
    int* csr_start = (int*)alloc((size_t)(N + 1) * 4);
    int* cnt_mat   = (int*)alloc((size_t)nb * BINB * 4);
    int* rowloc    = (int*)alloc((size_t)nb * BINB * 4);
    int* btot      = (int*)alloc((size_t)NBMAX * 4);
    int* bbase     = (int*)alloc((size_t)NBMAX * 4);
    int* gestart   = (int*)alloc(256 + 64);
    unsigned short* csr_src = (unsigned short*)alloc((size_t)E * 2);
    unsigned*       binned  = (unsigned*)alloc((size_t)E * 4);
    unsigned short* x_bf = (unsigned short*)alloc((size_t)N * 128 * 2 + 65536);
    unsigned short* hA   = (unsigned short*)alloc((size_t)N * 128 * 2 + 65536);
    unsigned char*  x8   = (unsigned char*)alloc((size_t)N * 128);
    unsigned char*  h1_8 = (unsigned char*)alloc((size_t)N * 128);
    unsigned char*  h2_8 = (unsigned char*)alloc((size_t)N * 128);
    unsigned char*  h2T  = (unsigned char*)alloc((size_t)128 * NSP);
    unsigned short* Whi = (unsigned short*)alloc(2 * 128 * 256 * 2);
    // cnt, gsumE, gsumP contiguous -> one memset
    unsigned* cnt  = (unsigned*)alloc((size_t)64 * NSP * 4);
    float* gsumE = (float*)alloc((size_t)64 * 128 * 4);
    float* gsumP = (float*)alloc((size_t)64 * 128 * 4);
    (void)ws_size;

    hipMemsetAsync(cnt, 0, (size_t)64 * NSP * 4 + (size_t)2 * 64 * 128 * 4, stream);

    // --- CSR build + casts + edge histogram (one wide launch) ---
    int n8 = N * 128 / 8;
    int nxblk = (n8 + 255) / 256;
    const int HISTB = 256;
    int hepb = (E + HISTB - 1) / HISTB;
    k_bincast<<<BINB + nxblk + 256 + HISTB, 256, 0, stream>>>(
        ei, cnt_mat, E, nb, epb,
        x, x_bf, x8, n8, nxblk, W1l, W1r, W2l, W2r, Whi,
        batch, cnt, NSP, hepb);
    k_mrowscan<<<nb, 256, 0, stream>>>(cnt_mat, rowloc, btot);
    k_scan2b<<<1, 256, 0, stream>>>(btot, bbase, nb, csr_start + N);
    k_binscatter<<<BINB, 256, 0, stream>>>(ei, rowloc, bbase, binned, E, nb, epb);
    k_fillfine2<<<nb, 256, 0, stream>>>(binned, bbase, batch, csr_start, csr_src,
                                        gestart, E, nb, N);

    int lay_grid  = (N + 15) / 16;    // 3125
    int lay2_grid = NSP / 16;         // 3126 (pad block zero-fills h2T tail)
    int pool_grid = (((N + 15) / 16) + 3) / 4;
    const int GB = 256;               // gsum GEMM K-split blocks

    // Layer 1: fused gather(x fp8) + GEMM -> h1 frags (relu) + h1 fp8 rows
    k_layer<<<lay_grid, 256, 0, stream>>>(x8, csr_start, csr_src, x_bf,
                                          Whi, b1l, hA, h1_8, h2T, N, NSP, 1, 0);
    // Layer 2: fused gather(h1 fp8) + GEMM -> h2 fp8 rows + transposed h2T
    k_layer<<<lay2_grid, 256, 0, stream>>>(h1_8, csr_start, csr_src, hA,
                                           Whi + 32768, b2l, hA, h2_8, h2T, N, NSP, 0, 1);
    // gsumE = cnt x h2T (MFMA GEMM) ; gsumP = node pool (branch)
    k_gsum<<<GB + pool_grid, 256, 0, stream>>>(cnt, h2T, h2_8, batch,
                                               gsumE, gsumP, N, NSP, KSTEPS, GB);

    // Head: (gsumE@W3l + gsumP@W3r)/cnt + b3 -> @Wlin + blin
    k_final<<<64, 128, 0, stream>>>(gsumE, gsumP, batch, W3l, b3l, W3r,
                                    Wlin, blin, (float*)d_out, N);
}

// Round 3
// 275.694 us; speedup vs baseline: 1.0452x; 1.0452x over previous
//
#include <hip/hip_runtime.h>

// HierarchicalGraphSAGE bf16-MFMA version, R21.
// N=50000, E=800000, D=128, OUT=64, G=64.
//
//  R21 vs R20 (which regressed 244->288 via random-atomic histogram):
//   - Histogram rebuilt from sorted CSR: block per (graph, 8K-s-chunk),
//     LDS-local atomics, coalesced bf16 writes. No global atomics.
//   - cnt table is 128 rows: rows 0..63 edge counts (gsumE), rows 64..127
//     mean-pool indicator (gsumP). One MFMA GEMM produces both; per-block
//     partials reduced in k_final. No output atomics, no memsets at all.
//   - h2T written as bf16 by layer-2 epilogue -> GEMM is pure load+MFMA.
//   - k_layer epilogues LDS-staged: coalesced uint4/uint2 dumps instead of
//     per-lane scalar 2B/1B stores (and R20's 8B-at-100KB-stride h2T).

typedef __bf16 bf16x8 __attribute__((ext_vector_type(8)));
typedef float f32x4 __attribute__((ext_vector_type(4)));
typedef float f32x2 __attribute__((ext_vector_type(2)));

#define BINB 160
#define NBMAX 512
#define CH 8192

static __device__ __forceinline__ unsigned short f2bf(float f) {
    unsigned u = __builtin_bit_cast(unsigned, f);
    return (unsigned short)((u + 0x7fffu + ((u >> 16) & 1u)) >> 16);
}
static __device__ __forceinline__ uint2 pk8_fp8(const float* f) {
    int lo = 0, hi = 0;
    lo = __builtin_amdgcn_cvt_pk_fp8_f32(f[0], f[1], lo, false);
    lo = __builtin_amdgcn_cvt_pk_fp8_f32(f[2], f[3], lo, true);
    hi = __builtin_amdgcn_cvt_pk_fp8_f32(f[4], f[5], hi, false);
    hi = __builtin_amdgcn_cvt_pk_fp8_f32(f[6], f[7], hi, true);
    return make_uint2((unsigned)lo, (unsigned)hi);
}
static __device__ __forceinline__ unsigned char f2fp8(float v) {
    return (unsigned char)(__builtin_amdgcn_cvt_pk_fp8_f32(v, v, 0, false) & 0xff);
}

// ---------------- bucket count + cast + weight pack ----------------
__global__ __launch_bounds__(256) void k_bincast(
    const int* __restrict__ ei, int* __restrict__ cnt_mat, int E, int nb, int epb,
    const float* __restrict__ x, unsigned short* __restrict__ xb,
    unsigned char* __restrict__ x8, int n8, int nxblk,
    const float* __restrict__ W1l, const float* __restrict__ W1r,
    const float* __restrict__ W2l, const float* __restrict__ W2r,
    unsigned short* __restrict__ Whi)
{
    __shared__ int lc[NBMAX];
    int bid = blockIdx.x;
    if (bid < BINB) {
        for (int i = threadIdx.x; i < nb; i += 256) lc[i] = 0;
        __syncthreads();
        int b0 = bid * epb;
        int b1 = min(b0 + epb, E);
        for (int i = b0 + threadIdx.x; i < b1; i += 256)
            atomicAdd(&lc[ei[E + i] >> 7], 1);
        __syncthreads();
        for (int i = threadIdx.x; i < nb; i += 256)
            cnt_mat[i * BINB + bid] = lc[i];
    } else if (bid < BINB + nxblk) {
        int i = (bid - BINB) * 256 + threadIdx.x;
        if (i >= n8) return;
        float f[8];
        *(float4*)(f + 0) = *(const float4*)(x + (size_t)i * 8);
        *(float4*)(f + 4) = *(const float4*)(x + (size_t)i * 8 + 4);
        ushort4 oa, ob;
        oa.x = f2bf(f[0]); oa.y = f2bf(f[1]); oa.z = f2bf(f[2]); oa.w = f2bf(f[3]);
        ob.x = f2bf(f[4]); ob.y = f2bf(f[5]); ob.z = f2bf(f[6]); ob.w = f2bf(f[7]);
        int node = i >> 4, c = i & 15;
        size_t dstb = (size_t)(node >> 4) * 2048 + (size_t)(c >> 2) * 512
                    + (size_t)((c & 3) * 16 + (node & 15)) * 8;
        *(ushort4*)(xb + dstb) = oa;
        *(ushort4*)(xb + dstb + 4) = ob;
        *(uint2*)(x8 + (size_t)i * 8) = pk8_fp8(f);
    } else {
        int wb = bid - BINB - nxblk;   // 0..255 (2 layers)
        int layer = wb >> 7;
        int j = wb & 127;
        int k = threadIdx.x;
        const float* Wl = (layer == 0) ? W1l : W2l;
        const float* Wr = (layer == 0) ? W1r : W2r;
        float w = (k < 128) ? Wl[j * 128 + k] : Wr[j * 128 + k - 128];
        int js = j >> 4, mr = j & 15;
        int s = k >> 5, quad = (k >> 3) & 3, e = k & 7;
        size_t o = (size_t)layer * 32768
                 + ((size_t)(js * 8 + s) * 64 + quad * 16 + mr) * 8 + e;
        Whi[o] = f2bf(w);
    }
}

__global__ __launch_bounds__(256) void k_mrowscan(
    const int* __restrict__ cnt_mat, int* __restrict__ rowloc, int* __restrict__ btot)
{
    __shared__ int s[256];
    int b = blockIdx.x;
    int t = threadIdx.x;
    int v = (t < BINB) ? cnt_mat[b * BINB + t] : 0;
    s[t] = v;
    __syncthreads();
#pragma unroll
    for (int off = 1; off < 256; off <<= 1) {
        int u = (t >= off) ? s[t - off] : 0;
        __syncthreads();
        s[t] += u;
        __syncthreads();
    }
    if (t < BINB) rowloc[b * BINB + t] = s[t] - v;
    if (t == 255) btot[b] = s[255];
}

__global__ __launch_bounds__(256) void k_scan2b(
    const int* __restrict__ btot, int* __restrict__ bbase, int nb, int* __restrict__ total_out)
{
    __shared__ int s[256];
    int t = threadIdx.x;
    int per = (nb + 255) / 256;
    int s0 = t * per, e0 = min(s0 + per, nb);
    int sum = 0;
    for (int i = s0; i < e0; ++i) sum += btot[i];
    s[t] = sum;
    __syncthreads();
#pragma unroll
    for (int off = 1; off < 256; off <<= 1) {
        int u = (t >= off) ? s[t - off] : 0;
        __syncthreads();
        s[t] += u;
        __syncthreads();
    }
    int run = s[t] - sum;
    for (int i = s0; i < e0; ++i) { bbase[i] = run; run += btot[i]; }
    if (t == 255) *total_out = s[255];
}

__global__ __launch_bounds__(256) void k_binscatter(
    const int* __restrict__ ei, const int* __restrict__ rowloc, const int* __restrict__ bbase,
    unsigned* __restrict__ binned, int E, int nb, int epb)
{
    __shared__ int lofs[NBMAX];
    __shared__ int lcnt[NBMAX];
    for (int i = threadIdx.x; i < nb; i += 256) {
        lofs[i] = rowloc[i * BINB + blockIdx.x] + bbase[i];
        lcnt[i] = 0;
    }
    __syncthreads();
    int b0 = blockIdx.x * epb;
    int b1 = min(b0 + epb, E);
    for (int i = b0 + threadIdx.x; i < b1; i += 256) {
        int s = ei[i];
        int d = ei[E + i];
        int b = d >> 7;
        int r = atomicAdd(&lcnt[b], 1);
        binned[lofs[b] + r] = (unsigned)s | ((unsigned)(d & 127) << 16);
    }
}

// Per-bucket fine stage + gestart fold.
__global__ __launch_bounds__(256) void k_fillfine2(
    const unsigned* __restrict__ binned, const int* __restrict__ bbase,
    const int* __restrict__ batch, int* __restrict__ starts,
    unsigned short* __restrict__ csr_src, int* __restrict__ gestart,
    int E, int nb, int n)
{
    __shared__ int lc[128];
    __shared__ int lpos[128];
    int b = blockIdx.x;
    int t = threadIdx.x;
    int node0 = b << 7;
    int bs = bbase[b];
    int be = (b == nb - 1) ? E : bbase[b + 1];
    if (t < 128) lc[t] = 0;
    __syncthreads();
    for (int i = bs + t; i < be; i += 256)
        atomicAdd(&lc[(binned[i] >> 16) & 127], 1);
    __syncthreads();
    int v = (t < 128) ? lc[t] : 0;
    if (t < 128) lpos[t] = v;
    __syncthreads();
#pragma unroll
    for (int off = 1; off < 128; off <<= 1) {
        int u = (t >= off && t < 128) ? lpos[t - off] : 0;
        __syncthreads();
        if (t < 128) lpos[t] += u;
        __syncthreads();
    }
    int excl = (t < 128) ? (lpos[t] - v) : 0;
    __syncthreads();
    if (t < 128) {
        int node = node0 + t;
        if (node < n) {
            int st = bs + excl;
            starts[node] = st;
            int bc = batch[node];
            int bp = (node == 0) ? -1 : batch[node - 1];
            for (int g = bp + 1; g <= bc; ++g) gestart[g] = st;
            if (node == n - 1)
                for (int g = bc + 1; g <= 64; ++g) gestart[g] = E;
        }
        lpos[t] = bs + excl;
    }
    if (b == nb - 1 && t == 0) starts[n] = E;
    __syncthreads();
    for (int i = bs + t; i < be; i += 256) {
        unsigned e = binned[i];
        int slot = atomicAdd(&lpos[(e >> 16) & 127], 1);
        csr_src[slot] = (unsigned short)(e & 0xffffu);
    }
}

// ---------------- histogram + pool-indicator table (bf16, 128 x nsp) -------
// bid = gr*nch + c. gr<64: hist of graph gr's src list into s-chunk c
// (LDS atomics, coalesced bf16 write). gr>=64: indicator batch[s]==gr-64.
__global__ __launch_bounds__(256) void k_hist(
    const unsigned short* __restrict__ csr, const int* __restrict__ gestart,
    const int* __restrict__ batch, unsigned short* __restrict__ cntb,
    int n, int nsp, int nch)
{
    __shared__ unsigned lc[CH];
    int bid = blockIdx.x;
    int c = bid % nch;
    int gr = bid / nch;
    int s0 = c * CH;
    int t = threadIdx.x;
    if (gr < 64) {
        for (int i = t; i < CH; i += 256) lc[i] = 0;
        __syncthreads();
        int e0 = gestart[gr], e1 = gestart[gr + 1];
        for (int i = e0 + t; i < e1; i += 256) {
            unsigned d = (unsigned)((int)csr[i] - s0);
            if (d < (unsigned)CH) atomicAdd(&lc[d], 1u);
        }
        __syncthreads();
        for (int i = t; i < CH; i += 256) {
            int s = s0 + i;
            if (s < nsp)
                cntb[(size_t)gr * nsp + s] = f2bf((float)lc[i]);
        }
    } else {
        int g2 = gr - 64;
        for (int i = t; i < CH; i += 256) {
            int s = s0 + i;
            if (s < nsp)
                cntb[(size_t)gr * nsp + s] =
                    (s < n && batch[s] == g2) ? (unsigned short)0x3f80 : (unsigned short)0;
        }
    }
}

// ---------------- shared gather helpers (f32x2 packed accumulators) --------
#define ACC8P(v)                                                        \
    do {                                                                \
        f32x2 p0 = __builtin_amdgcn_cvt_pk_f32_fp8((v).x, false);       \
        f32x2 p1 = __builtin_amdgcn_cvt_pk_f32_fp8((v).x, true);        \
        f32x2 p2 = __builtin_amdgcn_cvt_pk_f32_fp8((v).y, false);       \
        f32x2 p3 = __builtin_amdgcn_cvt_pk_f32_fp8((v).y, true);        \
        A01 += p0; A23 += p1; A45 += p2; A67 += p3;                     \
    } while (0)

#define PROC_CHUNK(idxv, cntv)                                          \
    {                                                                   \
        int j = 0;                                                      \
        for (; j + 16 <= (cntv); j += 16) {                             \
            int s0 = __shfl((int)(idxv), j + eg);                       \
            int s1 = __shfl((int)(idxv), j + 4 + eg);                   \
            int s2 = __shfl((int)(idxv), j + 8 + eg);                   \
            int s3 = __shfl((int)(idxv), j + 12 + eg);                  \
            uint2 v0 = *(const uint2*)(hrow + (size_t)s0 * 128);        \
            uint2 v1 = *(const uint2*)(hrow + (size_t)s1 * 128);        \
            uint2 v2 = *(const uint2*)(hrow + (size_t)s2 * 128);        \
            uint2 v3 = *(const uint2*)(hrow + (size_t)s3 * 128);        \
            ACC8P(v0);                                                  \
            ACC8P(v1);                                                  \
            ACC8P(v2);                                                  \
            ACC8P(v3);                                                  \
        }                                                               \
        for (; j + 4 <= (cntv); j += 4) {                               \
            int s0 = __shfl((int)(idxv), j + eg);                       \
            uint2 v0 = *(const uint2*)(hrow + (size_t)s0 * 128);        \
            ACC8P(v0);                                                  \
        }                                                               \
        if (j < (cntv)) {                                               \
            int k = j + eg;                                             \
            int sm = __shfl((int)(idxv), (k < (cntv)) ? k : ((cntv) - 1)); \
            uint2 v = *(const uint2*)(hrow + (size_t)sm * 128);         \
            if (k >= (cntv)) v = make_uint2(0u, 0u);                    \
            ACC8P(v);                                                   \
        }                                                               \
    }

#define REDUCE8()                                                       \
    a0 += __shfl_xor(a0, 16); a0 += __shfl_xor(a0, 32);                 \
    a1 += __shfl_xor(a1, 16); a1 += __shfl_xor(a1, 32);                 \
    a2 += __shfl_xor(a2, 16); a2 += __shfl_xor(a2, 32);                 \
    a3 += __shfl_xor(a3, 16); a3 += __shfl_xor(a3, 32);                 \
    a4 += __shfl_xor(a4, 16); a4 += __shfl_xor(a4, 32);                 \
    a5 += __shfl_xor(a5, 16); a5 += __shfl_xor(a5, 32);                 \
    a6 += __shfl_xor(a6, 16); a6 += __shfl_xor(a6, 32);                 \
    a7 += __shfl_xor(a7, 16); a7 += __shfl_xor(a7, 32);

// ---------------- fused SAGE layer: gather->LDS frags -> MFMA GEMM ---------
// 256 threads = 4 waves own 16 nodes. mode 0: write hA frags + fp8 rows
// (both LDS-staged, coalesced dump). mode 1: write bf16 h2T[col][node].
__global__ __launch_bounds__(256) void k_layer(
    const unsigned char* __restrict__ h8_in, const int* __restrict__ starts,
    const unsigned short* __restrict__ csr, const unsigned short* __restrict__ hf,
    const unsigned short* __restrict__ Whi, const float* __restrict__ bl,
    unsigned short* __restrict__ outf, unsigned char* __restrict__ out8,
    unsigned short* __restrict__ h2tb,
    int n, int nsp, int mode)
{
    __shared__ unsigned short sagg[2048];   // 4KB: agg frags, then epilogue tile
    __shared__ unsigned char s8[2048];      // 2KB: fp8 row tile (mode 0)
    int t = threadIdx.x;
    int wv = t >> 6;
    int lane = t & 63;
    int node0 = blockIdx.x * 16;

    // ---- gather phase ----
    {
        int eg = lane >> 4;
        int fb = lane & 15;
        const unsigned char* hrow = h8_in + fb * 8;
        int nodeA = node0 + wv * 4;
        int st[5];
#pragma unroll
        for (int r = 0; r < 5; ++r) {
            int nn = nodeA + r;
            st[r] = starts[nn > n ? n : nn];
        }
        unsigned idx4[4];
#pragma unroll
        for (int r = 0; r < 4; ++r)
            idx4[r] = (st[r] + lane < st[r + 1]) ? (unsigned)csr[st[r] + lane] : 0u;

#pragma unroll
        for (int r = 0; r < 4; ++r) {
            int node = nodeA + r;
            if (node >= n) break;
            f32x2 A01 = (f32x2){0.f, 0.f}, A23 = (f32x2){0.f, 0.f},
                  A45 = (f32x2){0.f, 0.f}, A67 = (f32x2){0.f, 0.f};
            int deg = st[r + 1] - st[r];
            int c0 = min(64, deg);
            PROC_CHUNK(idx4[r], c0)
            for (int base = st[r] + 64; base < st[r + 1]; base += 64) {
                int cnt2 = min(64, st[r + 1] - base);
                unsigned idx = (base + lane < st[r + 1]) ? (unsigned)csr[base + lane] : 0u;
                PROC_CHUNK(idx, cnt2)
            }
            float a0 = A01.x, a1 = A01.y, a2 = A23.x, a3 = A23.y,
                  a4 = A45.x, a5 = A45.y, a6 = A67.x, a7 = A67.y;
            REDUCE8()
            if (eg == 0) {
                int ln = node - node0;   // 0..15
                unsigned u0 = (unsigned)f2bf(a0) | ((unsigned)f2bf(a1) << 16);
                unsigned u1 = (unsigned)f2bf(a2) | ((unsigned)f2bf(a3) << 16);
                unsigned u2 = (unsigned)f2bf(a4) | ((unsigned)f2bf(a5) << 16);
                unsigned u3 = (unsigned)f2bf(a6) | ((unsigned)f2bf(a7) << 16);
                size_t dst = (size_t)(fb >> 2) * 512 + (size_t)((fb & 3) * 16 + ln) * 8;
                *(uint4*)(sagg + dst) = make_uint4(u0, u1, u2, u3);
            }
        }
    }
    __syncthreads();

    // ---- GEMM phase ----
    int quad = lane >> 4;
    int mr = lane & 15;
    int js0 = wv * 2;

    f32x4 acc0 = (f32x4){0.f, 0.f, 0.f, 0.f};
    f32x4 acc1 = (f32x4){0.f, 0.f, 0.f, 0.f};

    const unsigned short* wp = Whi + (size_t)js0 * 4096 + (size_t)lane * 8;
    const unsigned short* sa = sagg + (size_t)lane * 8;
    const unsigned short* ha = hf + (size_t)blockIdx.x * 2048 + (size_t)lane * 8;

    uint4 pb[2][3];
#define LAYER_LOAD(s, b)                                                  \
    do {                                                                  \
        pb[b][0] = *(const uint4*)(wp + (size_t)(s) * 512);               \
        pb[b][1] = *(const uint4*)(wp + 4096 + (size_t)(s) * 512);        \
        pb[b][2] = ((s) < 4)                                              \
            ? *(const uint4*)(sa + (size_t)(s) * 512)                     \
            : *(const uint4*)(ha + (size_t)((s) - 4) * 512);              \
    } while (0)

    LAYER_LOAD(0, 0);
    LAYER_LOAD(1, 1);
#pragma unroll
    for (int s = 0; s < 8; ++s) {
        int b = s & 1;
        bf16x8 bh0 = __builtin_bit_cast(bf16x8, pb[b][0]);
        bf16x8 bh1 = __builtin_bit_cast(bf16x8, pb[b][1]);
        bf16x8 A0 = __builtin_bit_cast(bf16x8, pb[b][2]);
        acc0 = __builtin_amdgcn_mfma_f32_16x16x32_bf16(A0, bh0, acc0, 0, 0, 0);
        acc1 = __builtin_amdgcn_mfma_f32_16x16x32_bf16(A0, bh1, acc1, 0, 0, 0);
        if (s + 2 < 8) LAYER_LOAD(s + 2, b);
    }
#undef LAYER_LOAD

    // ---- epilogue: bias/relu, LDS-stage, coalesced dump ----
    float vv[2][4];
#pragma unroll
    for (int mi = 0; mi < 2; ++mi) {
        f32x4 a = mi ? acc1 : acc0;
        int col = (js0 + mi) * 16 + mr;
        float bias = bl[col];
#pragma unroll
        for (int r = 0; r < 4; ++r) {
            int node = node0 + quad * 4 + r;
            float v = fmaxf(a[r] + bias, 0.f);
            vv[mi][r] = (node < n) ? v : 0.f;
        }
    }
    __syncthreads();   // sagg reuse: all waves done reading frags
    if (mode == 0) {
#pragma unroll
        for (int mi = 0; mi < 2; ++mi) {
            int col = (js0 + mi) * 16 + mr;
            int so = col >> 5, q2 = (col >> 3) & 3, e2 = col & 7;
#pragma unroll
            for (int r = 0; r < 4; ++r) {
                int nl = quad * 4 + r;
                sagg[so * 512 + (q2 * 16 + nl) * 8 + e2] = f2bf(vv[mi][r]);
                s8[nl * 128 + col] = f2fp8(vv[mi][r]);
            }
        }
        __syncthreads();
        *(uint4*)(outf + (size_t)blockIdx.x * 2048 + (size_t)t * 8) =
            *(const uint4*)(sagg + (size_t)t * 8);
        int nl = t >> 4;
        if (node0 + nl < n)
            *(uint2*)(out8 + (size_t)(node0 + nl) * 128 + (t & 15) * 8) =
                *(const uint2*)(s8 + nl * 128 + (t & 15) * 8);
    } else {
#pragma unroll
        for (int mi = 0; mi < 2; ++mi) {
            int col = (js0 + mi) * 16 + mr;
#pragma unroll
            for (int r = 0; r < 4; ++r)
                sagg[col * 16 + quad * 4 + r] = f2bf(vv[mi][r]);
        }
        __syncthreads();
        int col = t >> 1;
        *(uint4*)(h2tb + (size_t)col * nsp + node0 + (t & 1) * 8) =
            *(const uint4*)(sagg + col * 16 + (t & 1) * 8);
    }
}

// ---------------- gsum GEMM: [128 x nsp] cntb x h2tb^T -> per-block partials
// A rows 0..63: edge counts (gsumE); rows 64..127: pool indicator (gsumP).
__global__ __launch_bounds__(256) void k_gsum(
    const unsigned short* __restrict__ cntb, const unsigned short* __restrict__ h2tb,
    float* __restrict__ part, int nsp, int ksteps, int gb)
{
    int t = threadIdx.x;
    int wv = t >> 6, lane = t & 63;
    int fast = lane & 15;
    int kc = (lane >> 4) * 8;
    int kpb = (ksteps + gb - 1) / gb;
    int k0 = blockIdx.x * kpb, k1 = min(k0 + kpb, ksteps);

    f32x4 accE[8], accP[8];
#pragma unroll
    for (int i = 0; i < 8; ++i) {
        accE[i] = (f32x4){0.f, 0.f, 0.f, 0.f};
        accP[i] = (f32x4){0.f, 0.f, 0.f, 0.f};
    }

    const unsigned short* apE = cntb + (size_t)(wv * 16 + fast) * nsp + kc;
    const unsigned short* apP = apE + (size_t)64 * nsp;
    const unsigned short* bp  = h2tb + (size_t)fast * nsp + kc;

    if (k0 < k1) {
        int kb = k0 * 32;
        uint4 ca0 = *(const uint4*)(apE + kb);
        uint4 ca1 = *(const uint4*)(apP + kb);
        uint4 cb[8];
#pragma unroll
        for (int ft = 0; ft < 8; ++ft)
            cb[ft] = *(const uint4*)(bp + (size_t)ft * 16 * nsp + kb);
        for (int ks = k0; ks < k1; ++ks) {
            int kn = min(ks + 1, k1 - 1) * 32;
            uint4 na0 = *(const uint4*)(apE + kn);
            uint4 na1 = *(const uint4*)(apP + kn);
            uint4 nb[8];
#pragma unroll
            for (int ft = 0; ft < 8; ++ft)
                nb[ft] = *(const uint4*)(bp + (size_t)ft * 16 * nsp + kn);
            bf16x8 aE = __builtin_bit_cast(bf16x8, ca0);
            bf16x8 aP = __builtin_bit_cast(bf16x8, ca1);
#pragma unroll
            for (int ft = 0; ft < 8; ++ft) {
                bf16x8 bf = __builtin_bit_cast(bf16x8, cb[ft]);
                accE[ft] = __builtin_amdgcn_mfma_f32_16x16x32_bf16(aE, bf, accE[ft], 0, 0, 0);
                accP[ft] = __builtin_amdgcn_mfma_f32_16x16x32_bf16(aP, bf, accP[ft], 0, 0, 0);
            }
            ca0 = na0; ca1 = na1;
#pragma unroll
            for (int ft = 0; ft < 8; ++ft) cb[ft] = nb[ft];
        }
    }
    float* po = part + (size_t)blockIdx.x * 16384;
    int quad = lane >> 4, mr = lane & 15;
#pragma unroll
    for (int ft = 0; ft < 8; ++ft) {
        int col = ft * 16 + mr;
#pragma unroll
        for (int r = 0; r < 4; ++r) {
            po[(size_t)(wv * 16 + quad * 4 + r) * 128 + col] = accE[ft][r];
            po[(size_t)(64 + wv * 16 + quad * 4 + r) * 128 + col] = accP[ft][r];
        }
    }
}

// ---------------- final: partial reduce + collapsed layer 3 + head ---------
__global__ __launch_bounds__(128) void k_final(
    const float* __restrict__ part, const int* __restrict__ batch,
    const float* __restrict__ W3l, const float* __restrict__ b3,
    const float* __restrict__ W3r,
    const float* __restrict__ Wlin, const float* __restrict__ blin,
    float* __restrict__ out, int n, int gb)
{
    __shared__ float sE[128], sP[128], tmp[128];
    int g = blockIdx.x;   // 64
    int t = threadIdx.x;  // 128
    float se = 0.f, sp = 0.f;
    for (int p = 0; p < gb; ++p) {
        const float* pp = part + (size_t)p * 16384;
        se += pp[g * 128 + t];
        sp += pp[(64 + g) * 128 + t];
    }
    sE[t] = se;
    sP[t] = sp;

    int lo = 0, hi = n;
    while (lo < hi) { int m = (lo + hi) >> 1; if (batch[m] < g) lo = m + 1; else hi = m; }
    int lb = lo;
    hi = n;
    while (lo < hi) { int m = (lo + hi) >> 1; if (batch[m] < g + 1) lo = m + 1; else hi = m; }
    int cnt = lo - lb;
    float inv = (cnt > 0) ? 1.f / (float)cnt : 0.f;
    __syncthreads();

    float acc = 0.f;
    for (int k = 0; k < 128; ++k)
        acc += sE[k] * W3l[t * 128 + k] + sP[k] * W3r[t * 128 + k];
    tmp[t] = acc * inv + ((cnt > 0) ? b3[t] : 0.f);
    __syncthreads();

    if (t < 64) {
        float o = 0.f;
        for (int k = 0; k < 128; ++k)
            o += tmp[k] * Wlin[t * 128 + k];
        out[g * 64 + t] = o + blin[t];
    }
}

extern "C" void kernel_launch(void* const* d_in, const int* in_sizes, int n_in,
                              void* d_out, int out_size, void* d_ws, size_t ws_size,
                              hipStream_t stream) {
    const float* x     = (const float*)d_in[0];
    const int*   ei    = (const int*)d_in[1];
    const int*   batch = (const int*)d_in[2];
    const float* W1l = (const float*)d_in[3];
    const float* b1l = (const float*)d_in[4];
    const float* W1r = (const float*)d_in[5];
    const float* W2l = (const float*)d_in[6];
    const float* b2l = (const float*)d_in[7];
    const float* W2r = (const float*)d_in[8];
    const float* W3l = (const float*)d_in[9];
    const float* b3l = (const float*)d_in[10];
    const float* W3r = (const float*)d_in[11];
    const float* Wlin = (const float*)d_in[12];
    const float* blin = (const float*)d_in[13];

    const int N = in_sizes[2];       // 50000
    const int E = in_sizes[1] / 2;   // 800000
    const int nb = (N + 127) >> 7;   // 391 buckets
    const int epb = (E + BINB - 1) / BINB;
    const int NSP = ((N + 31) / 32) * 32;        // 50016 (mult of 32)
    const int KSTEPS = NSP / 32;                 // 1563
    const int NCH = (NSP + CH - 1) / CH;         // 7
    const int GB = 128;                          // gsum K-split blocks

    size_t off = 0;
    auto alloc = [&](size_t bytes) {
        void* p = (char*)d_ws + off;
        off += (bytes + 255) & ~(size_t)255;
        return p;
    };
    int* csr_start = (int*)alloc((size_t)(N + 1) * 4);
    int* cnt_mat   = (int*)alloc((size_t)nb * BINB * 4);
    int* rowloc    = (int*)alloc((size_t)nb * BINB * 4);
    int* btot      = (int*)alloc((size_t)NBMAX * 4);
    int* bbase     = (int*)alloc((size_t)NBMAX * 4);
    int* gestart   = (int*)alloc(256 + 64);
    unsigned short* csr_src = (unsigned short*)alloc((size_t)E * 2);
    unsigned*       binned  = (unsigned*)alloc((size_t)E * 4);
    unsigned short* x_bf = (unsigned short*)alloc((size_t)N * 128 * 2 + 65536);
    unsigned short* hA   = (unsigned short*)alloc((size_t)N * 128 * 2 + 65536);
    unsigned char*  x8   = (unsigned char*)alloc((size_t)N * 128);
    unsigned char*  h1_8 = (unsigned char*)alloc((size_t)N * 128);
    unsigned short* h2Tb = (unsigned short*)alloc((size_t)128 * NSP * 2);
    unsigned short* cntb = (unsigned short*)alloc((size_t)128 * NSP * 2);
    unsigned short* Whi  = (unsigned short*)alloc(2 * 128 * 256 * 2);
    float*          part = (float*)alloc((size_t)GB * 16384 * 4);
    (void)ws_size;

    // --- CSR build + casts (no memsets anywhere) ---
    int n8 = N * 128 / 8;
    int nxblk = (n8 + 255) / 256;
    k_bincast<<<BINB + nxblk + 256, 256, 0, stream>>>(
        ei, cnt_mat, E, nb, epb,
        x, x_bf, x8, n8, nxblk, W1l, W1r, W2l, W2r, Whi);
    k_mrowscan<<<nb, 256, 0, stream>>>(cnt_mat, rowloc, btot);
    k_scan2b<<<1, 256, 0, stream>>>(btot, bbase, nb, csr_start + N);
    k_binscatter<<<BINB, 256, 0, stream>>>(ei, rowloc, bbase, binned, E, nb, epb);
    k_fillfine2<<<nb, 256, 0, stream>>>(binned, bbase, batch, csr_start, csr_src,
                                        gestart, E, nb, N);
    // count + indicator table from sorted CSR (LDS-local, no global atomics)
    k_hist<<<128 * NCH, 256, 0, stream>>>(csr_src, gestart, batch, cntb, N, NSP, NCH);

    int lay_grid  = (N + 15) / 16;    // 3125
    int lay2_grid = NSP / 16;         // 3126 (pad block zero-fills h2Tb tail)

    // Layer 1: fused gather(x fp8) + GEMM -> h1 frags (relu) + h1 fp8 rows
    k_layer<<<lay_grid, 256, 0, stream>>>(x8, csr_start, csr_src, x_bf,
                                          Whi, b1l, hA, h1_8, h2Tb, N, NSP, 0);
    // Layer 2: fused gather(h1 fp8) + GEMM -> bf16 h2T only
    k_layer<<<lay2_grid, 256, 0, stream>>>(h1_8, csr_start, csr_src, hA,
                                           Whi + 32768, b2l, hA, h1_8, h2Tb, N, NSP, 1);
    // gsumE+gsumP as one 128x128xNSP MFMA GEMM -> per-block partials
    k_gsum<<<GB, 256, 0, stream>>>(cntb, h2Tb, part, NSP, KSTEPS, GB);

    // Head: reduce partials + (gsumE@W3l + gsumP@W3r)/cnt + b3 -> @Wlin + blin
    k_final<<<64, 128, 0, stream>>>(part, batch, W3l, b3l, W3r,
                                    Wlin, blin, (float*)d_out, N, GB);
}

// Round 4
// 257.706 us; speedup vs baseline: 1.1181x; 1.0698x over previous
//
#include <hip/hip_runtime.h>

// HierarchicalGraphSAGE bf16-MFMA version, R22.
// N=50000, E=800000, D=128, OUT=64, G=64.
//
//  R22 vs R21 (275us; k_final was 45us latency-bound partial-reduce):
//   - k_reduce: dedicated coalesced reduction of the GB partials (16384
//     threads, thread i sums part[p*16384+i]) -> ~3us; k_final reads the
//     64KB reduced table (45us -> ~4us).
//   - k_layer: removed the data-dependent `break` in the 4-node gather
//     loop (clamped st[] makes deg=0 for pad nodes; zero frags harmless)
//     so the 4 independent gather chains software-pipeline.

typedef __bf16 bf16x8 __attribute__((ext_vector_type(8)));
typedef float f32x4 __attribute__((ext_vector_type(4)));
typedef float f32x2 __attribute__((ext_vector_type(2)));

#define BINB 160
#define NBMAX 512
#define CH 8192

static __device__ __forceinline__ unsigned short f2bf(float f) {
    unsigned u = __builtin_bit_cast(unsigned, f);
    return (unsigned short)((u + 0x7fffu + ((u >> 16) & 1u)) >> 16);
}
static __device__ __forceinline__ uint2 pk8_fp8(const float* f) {
    int lo = 0, hi = 0;
    lo = __builtin_amdgcn_cvt_pk_fp8_f32(f[0], f[1], lo, false);
    lo = __builtin_amdgcn_cvt_pk_fp8_f32(f[2], f[3], lo, true);
    hi = __builtin_amdgcn_cvt_pk_fp8_f32(f[4], f[5], hi, false);
    hi = __builtin_amdgcn_cvt_pk_fp8_f32(f[6], f[7], hi, true);
    return make_uint2((unsigned)lo, (unsigned)hi);
}
static __device__ __forceinline__ unsigned char f2fp8(float v) {
    return (unsigned char)(__builtin_amdgcn_cvt_pk_fp8_f32(v, v, 0, false) & 0xff);
}

// ---------------- bucket count + cast + weight pack ----------------
__global__ __launch_bounds__(256) void k_bincast(
    const int* __restrict__ ei, int* __restrict__ cnt_mat, int E, int nb, int epb,
    const float* __restrict__ x, unsigned short* __restrict__ xb,
    unsigned char* __restrict__ x8, int n8, int nxblk,
    const float* __restrict__ W1l, const float* __restrict__ W1r,
    const float* __restrict__ W2l, const float* __restrict__ W2r,
    unsigned short* __restrict__ Whi)
{
    __shared__ int lc[NBMAX];
    int bid = blockIdx.x;
    if (bid < BINB) {
        for (int i = threadIdx.x; i < nb; i += 256) lc[i] = 0;
        __syncthreads();
        int b0 = bid * epb;
        int b1 = min(b0 + epb, E);
        for (int i = b0 + threadIdx.x; i < b1; i += 256)
            atomicAdd(&lc[ei[E + i] >> 7], 1);
        __syncthreads();
        for (int i = threadIdx.x; i < nb; i += 256)
            cnt_mat[i * BINB + bid] = lc[i];
    } else if (bid < BINB + nxblk) {
        int i = (bid - BINB) * 256 + threadIdx.x;
        if (i >= n8) return;
        float f[8];
        *(float4*)(f + 0) = *(const float4*)(x + (size_t)i * 8);
        *(float4*)(f + 4) = *(const float4*)(x + (size_t)i * 8 + 4);
        ushort4 oa, ob;
        oa.x = f2bf(f[0]); oa.y = f2bf(f[1]); oa.z = f2bf(f[2]); oa.w = f2bf(f[3]);
        ob.x = f2bf(f[4]); ob.y = f2bf(f[5]); ob.z = f2bf(f[6]); ob.w = f2bf(f[7]);
        int node = i >> 4, c = i & 15;
        size_t dstb = (size_t)(node >> 4) * 2048 + (size_t)(c >> 2) * 512
                    + (size_t)((c & 3) * 16 + (node & 15)) * 8;
        *(ushort4*)(xb + dstb) = oa;
        *(ushort4*)(xb + dstb + 4) = ob;
        *(uint2*)(x8 + (size_t)i * 8) = pk8_fp8(f);
    } else {
        int wb = bid - BINB - nxblk;   // 0..255 (2 layers)
        int layer = wb >> 7;
        int j = wb & 127;
        int k = threadIdx.x;
        const float* Wl = (layer == 0) ? W1l : W2l;
        const float* Wr = (layer == 0) ? W1r : W2r;
        float w = (k < 128) ? Wl[j * 128 + k] : Wr[j * 128 + k - 128];
        int js = j >> 4, mr = j & 15;
        int s = k >> 5, quad = (k >> 3) & 3, e = k & 7;
        size_t o = (size_t)layer * 32768
                 + ((size_t)(js * 8 + s) * 64 + quad * 16 + mr) * 8 + e;
        Whi[o] = f2bf(w);
    }
}

__global__ __launch_bounds__(256) void k_mrowscan(
    const int* __restrict__ cnt_mat, int* __restrict__ rowloc, int* __restrict__ btot)
{
    __shared__ int s[256];
    int b = blockIdx.x;
    int t = threadIdx.x;
    int v = (t < BINB) ? cnt_mat[b * BINB + t] : 0;
    s[t] = v;
    __syncthreads();
#pragma unroll
    for (int off = 1; off < 256; off <<= 1) {
        int u = (t >= off) ? s[t - off] : 0;
        __syncthreads();
        s[t] += u;
        __syncthreads();
    }
    if (t < BINB) rowloc[b * BINB + t] = s[t] - v;
    if (t == 255) btot[b] = s[255];
}

__global__ __launch_bounds__(256) void k_scan2b(
    const int* __restrict__ btot, int* __restrict__ bbase, int nb, int* __restrict__ total_out)
{
    __shared__ int s[256];
    int t = threadIdx.x;
    int per = (nb + 255) / 256;
    int s0 = t * per, e0 = min(s0 + per, nb);
    int sum = 0;
    for (int i = s0; i < e0; ++i) sum += btot[i];
    s[t] = sum;
    __syncthreads();
#pragma unroll
    for (int off = 1; off < 256; off <<= 1) {
        int u = (t >= off) ? s[t - off] : 0;
        __syncthreads();
        s[t] += u;
        __syncthreads();
    }
    int run = s[t] - sum;
    for (int i = s0; i < e0; ++i) { bbase[i] = run; run += btot[i]; }
    if (t == 255) *total_out = s[255];
}

__global__ __launch_bounds__(256) void k_binscatter(
    const int* __restrict__ ei, const int* __restrict__ rowloc, const int* __restrict__ bbase,
    unsigned* __restrict__ binned, int E, int nb, int epb)
{
    __shared__ int lofs[NBMAX];
    __shared__ int lcnt[NBMAX];
    for (int i = threadIdx.x; i < nb; i += 256) {
        lofs[i] = rowloc[i * BINB + blockIdx.x] + bbase[i];
        lcnt[i] = 0;
    }
    __syncthreads();
    int b0 = blockIdx.x * epb;
    int b1 = min(b0 + epb, E);
    for (int i = b0 + threadIdx.x; i < b1; i += 256) {
        int s = ei[i];
        int d = ei[E + i];
        int b = d >> 7;
        int r = atomicAdd(&lcnt[b], 1);
        binned[lofs[b] + r] = (unsigned)s | ((unsigned)(d & 127) << 16);
    }
}

// Per-bucket fine stage + gestart fold.
__global__ __launch_bounds__(256) void k_fillfine2(
    const unsigned* __restrict__ binned, const int* __restrict__ bbase,
    const int* __restrict__ batch, int* __restrict__ starts,
    unsigned short* __restrict__ csr_src, int* __restrict__ gestart,
    int E, int nb, int n)
{
    __shared__ int lc[128];
    __shared__ int lpos[128];
    int b = blockIdx.x;
    int t = threadIdx.x;
    int node0 = b << 7;
    int bs = bbase[b];
    int be = (b == nb - 1) ? E : bbase[b + 1];
    if (t < 128) lc[t] = 0;
    __syncthreads();
    for (int i = bs + t; i < be; i += 256)
        atomicAdd(&lc[(binned[i] >> 16) & 127], 1);
    __syncthreads();
    int v = (t < 128) ? lc[t] : 0;
    if (t < 128) lpos[t] = v;
    __syncthreads();
#pragma unroll
    for (int off = 1; off < 128; off <<= 1) {
        int u = (t >= off && t < 128) ? lpos[t - off] : 0;
        __syncthreads();
        if (t < 128) lpos[t] += u;
        __syncthreads();
    }
    int excl = (t < 128) ? (lpos[t] - v) : 0;
    __syncthreads();
    if (t < 128) {
        int node = node0 + t;
        if (node < n) {
            int st = bs + excl;
            starts[node] = st;
            int bc = batch[node];
            int bp = (node == 0) ? -1 : batch[node - 1];
            for (int g = bp + 1; g <= bc; ++g) gestart[g] = st;
            if (node == n - 1)
                for (int g = bc + 1; g <= 64; ++g) gestart[g] = E;
        }
        lpos[t] = bs + excl;
    }
    if (b == nb - 1 && t == 0) starts[n] = E;
    __syncthreads();
    for (int i = bs + t; i < be; i += 256) {
        unsigned e = binned[i];
        int slot = atomicAdd(&lpos[(e >> 16) & 127], 1);
        csr_src[slot] = (unsigned short)(e & 0xffffu);
    }
}

// ---------------- histogram + pool-indicator table (bf16, 128 x nsp) -------
__global__ __launch_bounds__(256) void k_hist(
    const unsigned short* __restrict__ csr, const int* __restrict__ gestart,
    const int* __restrict__ batch, unsigned short* __restrict__ cntb,
    int n, int nsp, int nch)
{
    __shared__ unsigned lc[CH];
    int bid = blockIdx.x;
    int c = bid % nch;
    int gr = bid / nch;
    int s0 = c * CH;
    int t = threadIdx.x;
    if (gr < 64) {
        for (int i = t; i < CH; i += 256) lc[i] = 0;
        __syncthreads();
        int e0 = gestart[gr], e1 = gestart[gr + 1];
        for (int i = e0 + t; i < e1; i += 256) {
            unsigned d = (unsigned)((int)csr[i] - s0);
            if (d < (unsigned)CH) atomicAdd(&lc[d], 1u);
        }
        __syncthreads();
        for (int i = t; i < CH; i += 256) {
            int s = s0 + i;
            if (s < nsp)
                cntb[(size_t)gr * nsp + s] = f2bf((float)lc[i]);
        }
    } else {
        int g2 = gr - 64;
        for (int i = t; i < CH; i += 256) {
            int s = s0 + i;
            if (s < nsp)
                cntb[(size_t)gr * nsp + s] =
                    (s < n && batch[s] == g2) ? (unsigned short)0x3f80 : (unsigned short)0;
        }
    }
}

// ---------------- shared gather helpers (f32x2 packed accumulators) --------
#define ACC8P(v)                                                        \
    do {                                                                \
        f32x2 p0 = __builtin_amdgcn_cvt_pk_f32_fp8((v).x, false);       \
        f32x2 p1 = __builtin_amdgcn_cvt_pk_f32_fp8((v).x, true);        \
        f32x2 p2 = __builtin_amdgcn_cvt_pk_f32_fp8((v).y, false);       \
        f32x2 p3 = __builtin_amdgcn_cvt_pk_f32_fp8((v).y, true);        \
        A01 += p0; A23 += p1; A45 += p2; A67 += p3;                     \
    } while (0)

#define PROC_CHUNK(idxv, cntv)                                          \
    {                                                                   \
        int j = 0;                                                      \
        for (; j + 16 <= (cntv); j += 16) {                             \
            int s0 = __shfl((int)(idxv), j + eg);                       \
            int s1 = __shfl((int)(idxv), j + 4 + eg);                   \
            int s2 = __shfl((int)(idxv), j + 8 + eg);                   \
            int s3 = __shfl((int)(idxv), j + 12 + eg);                  \
            uint2 v0 = *(const uint2*)(hrow + (size_t)s0 * 128);        \
            uint2 v1 = *(const uint2*)(hrow + (size_t)s1 * 128);        \
            uint2 v2 = *(const uint2*)(hrow + (size_t)s2 * 128);        \
            uint2 v3 = *(const uint2*)(hrow + (size_t)s3 * 128);        \
            ACC8P(v0);                                                  \
            ACC8P(v1);                                                  \
            ACC8P(v2);                                                  \
            ACC8P(v3);                                                  \
        }                                                               \
        for (; j + 4 <= (cntv); j += 4) {                               \
            int s0 = __shfl((int)(idxv), j + eg);                       \
            uint2 v0 = *(const uint2*)(hrow + (size_t)s0 * 128);        \
            ACC8P(v0);                                                  \
        }                                                               \
        if (j < (cntv)) {                                               \
            int k = j + eg;                                             \
            int sm = __shfl((int)(idxv), (k < (cntv)) ? k : ((cntv) - 1)); \
            uint2 v = *(const uint2*)(hrow + (size_t)sm * 128);         \
            if (k >= (cntv)) v = make_uint2(0u, 0u);                    \
            ACC8P(v);                                                   \
        }                                                               \
    }

#define REDUCE8()                                                       \
    a0 += __shfl_xor(a0, 16); a0 += __shfl_xor(a0, 32);                 \
    a1 += __shfl_xor(a1, 16); a1 += __shfl_xor(a1, 32);                 \
    a2 += __shfl_xor(a2, 16); a2 += __shfl_xor(a2, 32);                 \
    a3 += __shfl_xor(a3, 16); a3 += __shfl_xor(a3, 32);                 \
    a4 += __shfl_xor(a4, 16); a4 += __shfl_xor(a4, 32);                 \
    a5 += __shfl_xor(a5, 16); a5 += __shfl_xor(a5, 32);                 \
    a6 += __shfl_xor(a6, 16); a6 += __shfl_xor(a6, 32);                 \
    a7 += __shfl_xor(a7, 16); a7 += __shfl_xor(a7, 32);

// ---------------- fused SAGE layer: gather->LDS frags -> MFMA GEMM ---------
__global__ __launch_bounds__(256) void k_layer(
    const unsigned char* __restrict__ h8_in, const int* __restrict__ starts,
    const unsigned short* __restrict__ csr, const unsigned short* __restrict__ hf,
    const unsigned short* __restrict__ Whi, const float* __restrict__ bl,
    unsigned short* __restrict__ outf, unsigned char* __restrict__ out8,
    unsigned short* __restrict__ h2tb,
    int n, int nsp, int mode)
{
    __shared__ unsigned short sagg[2048];   // 4KB: agg frags, then epilogue tile
    __shared__ unsigned char s8[2048];      // 2KB: fp8 row tile (mode 0)
    int t = threadIdx.x;
    int wv = t >> 6;
    int lane = t & 63;
    int node0 = blockIdx.x * 16;

    // ---- gather phase ----
    {
        int eg = lane >> 4;
        int fb = lane & 15;
        const unsigned char* hrow = h8_in + fb * 8;
        int nodeA = node0 + wv * 4;
        int st[5];
#pragma unroll
        for (int r = 0; r < 5; ++r) {
            int nn = nodeA + r;
            st[r] = starts[nn > n ? n : nn];
        }
        unsigned idx4[4];
#pragma unroll
        for (int r = 0; r < 4; ++r)
            idx4[r] = (st[r] + lane < st[r + 1]) ? (unsigned)csr[st[r] + lane] : 0u;

#pragma unroll
        for (int r = 0; r < 4; ++r) {
            // pad nodes: st[r+1]==st[r] -> zero frags written (harmless)
            f32x2 A01 = (f32x2){0.f, 0.f}, A23 = (f32x2){0.f, 0.f},
                  A45 = (f32x2){0.f, 0.f}, A67 = (f32x2){0.f, 0.f};
            int deg = st[r + 1] - st[r];
            int c0 = min(64, deg);
            PROC_CHUNK(idx4[r], c0)
            for (int base = st[r] + 64; base < st[r + 1]; base += 64) {
                int cnt2 = min(64, st[r + 1] - base);
                unsigned idx = (base + lane < st[r + 1]) ? (unsigned)csr[base + lane] : 0u;
                PROC_CHUNK(idx, cnt2)
            }
            float a0 = A01.x, a1 = A01.y, a2 = A23.x, a3 = A23.y,
                  a4 = A45.x, a5 = A45.y, a6 = A67.x, a7 = A67.y;
            REDUCE8()
            if (eg == 0) {
                int ln = wv * 4 + r;   // 0..15
                unsigned u0 = (unsigned)f2bf(a0) | ((unsigned)f2bf(a1) << 16);
                unsigned u1 = (unsigned)f2bf(a2) | ((unsigned)f2bf(a3) << 16);
                unsigned u2 = (unsigned)f2bf(a4) | ((unsigned)f2bf(a5) << 16);
                unsigned u3 = (unsigned)f2bf(a6) | ((unsigned)f2bf(a7) << 16);
                size_t dst = (size_t)(fb >> 2) * 512 + (size_t)((fb & 3) * 16 + ln) * 8;
                *(uint4*)(sagg + dst) = make_uint4(u0, u1, u2, u3);
            }
        }
    }
    __syncthreads();

    // ---- GEMM phase ----
    int quad = lane >> 4;
    int mr = lane & 15;
    int js0 = wv * 2;

    f32x4 acc0 = (f32x4){0.f, 0.f, 0.f, 0.f};
    f32x4 acc1 = (f32x4){0.f, 0.f, 0.f, 0.f};

    const unsigned short* wp = Whi + (size_t)js0 * 4096 + (size_t)lane * 8;
    const unsigned short* sa = sagg + (size_t)lane * 8;
    const unsigned short* ha = hf + (size_t)blockIdx.x * 2048 + (size_t)lane * 8;

    uint4 pb[2][3];
#define LAYER_LOAD(s, b)                                                  \
    do {                                                                  \
        pb[b][0] = *(const uint4*)(wp + (size_t)(s) * 512);               \
        pb[b][1] = *(const uint4*)(wp + 4096 + (size_t)(s) * 512);        \
        pb[b][2] = ((s) < 4)                                              \
            ? *(const uint4*)(sa + (size_t)(s) * 512)                     \
            : *(const uint4*)(ha + (size_t)((s) - 4) * 512);              \
    } while (0)

    LAYER_LOAD(0, 0);
    LAYER_LOAD(1, 1);
#pragma unroll
    for (int s = 0; s < 8; ++s) {
        int b = s & 1;
        bf16x8 bh0 = __builtin_bit_cast(bf16x8, pb[b][0]);
        bf16x8 bh1 = __builtin_bit_cast(bf16x8, pb[b][1]);
        bf16x8 A0 = __builtin_bit_cast(bf16x8, pb[b][2]);
        acc0 = __builtin_amdgcn_mfma_f32_16x16x32_bf16(A0, bh0, acc0, 0, 0, 0);
        acc1 = __builtin_amdgcn_mfma_f32_16x16x32_bf16(A0, bh1, acc1, 0, 0, 0);
        if (s + 2 < 8) LAYER_LOAD(s + 2, b);
    }
#undef LAYER_LOAD

    // ---- epilogue: bias/relu, LDS-stage, coalesced dump ----
    float vv[2][4];
#pragma unroll
    for (int mi = 0; mi < 2; ++mi) {
        f32x4 a = mi ? acc1 : acc0;
        int col = (js0 + mi) * 16 + mr;
        float bias = bl[col];
#pragma unroll
        for (int r = 0; r < 4; ++r) {
            int node = node0 + quad * 4 + r;
            float v = fmaxf(a[r] + bias, 0.f);
            vv[mi][r] = (node < n) ? v : 0.f;
        }
    }
    __syncthreads();   // sagg reuse: all waves done reading frags
    if (mode == 0) {
#pragma unroll
        for (int mi = 0; mi < 2; ++mi) {
            int col = (js0 + mi) * 16 + mr;
            int so = col >> 5, q2 = (col >> 3) & 3, e2 = col & 7;
#pragma unroll
            for (int r = 0; r < 4; ++r) {
                int nl = quad * 4 + r;
                sagg[so * 512 + (q2 * 16 + nl) * 8 + e2] = f2bf(vv[mi][r]);
                s8[nl * 128 + col] = f2fp8(vv[mi][r]);
            }
        }
        __syncthreads();
        *(uint4*)(outf + (size_t)blockIdx.x * 2048 + (size_t)t * 8) =
            *(const uint4*)(sagg + (size_t)t * 8);
        int nl = t >> 4;
        if (node0 + nl < n)
            *(uint2*)(out8 + (size_t)(node0 + nl) * 128 + (t & 15) * 8) =
                *(const uint2*)(s8 + nl * 128 + (t & 15) * 8);
    } else {
#pragma unroll
        for (int mi = 0; mi < 2; ++mi) {
            int col = (js0 + mi) * 16 + mr;
#pragma unroll
            for (int r = 0; r < 4; ++r)
                sagg[col * 16 + quad * 4 + r] = f2bf(vv[mi][r]);
        }
        __syncthreads();
        int col = t >> 1;
        *(uint4*)(h2tb + (size_t)col * nsp + node0 + (t & 1) * 8) =
            *(const uint4*)(sagg + col * 16 + (t & 1) * 8);
    }
}

// ---------------- gsum GEMM: [128 x nsp] cntb x h2tb^T -> per-block partials
__global__ __launch_bounds__(256) void k_gsum(
    const unsigned short* __restrict__ cntb, const unsigned short* __restrict__ h2tb,
    float* __restrict__ part, int nsp, int ksteps, int gb)
{
    int t = threadIdx.x;
    int wv = t >> 6, lane = t & 63;
    int fast = lane & 15;
    int kc = (lane >> 4) * 8;
    int kpb = (ksteps + gb - 1) / gb;
    int k0 = blockIdx.x * kpb, k1 = min(k0 + kpb, ksteps);

    f32x4 accE[8], accP[8];
#pragma unroll
    for (int i = 0; i < 8; ++i) {
        accE[i] = (f32x4){0.f, 0.f, 0.f, 0.f};
        accP[i] = (f32x4){0.f, 0.f, 0.f, 0.f};
    }

    const unsigned short* apE = cntb + (size_t)(wv * 16 + fast) * nsp + kc;
    const unsigned short* apP = apE + (size_t)64 * nsp;
    const unsigned short* bp  = h2tb + (size_t)fast * nsp + kc;

    if (k0 < k1) {
        int kb = k0 * 32;
        uint4 ca0 = *(const uint4*)(apE + kb);
        uint4 ca1 = *(const uint4*)(apP + kb);
        uint4 cb[8];
#pragma unroll
        for (int ft = 0; ft < 8; ++ft)
            cb[ft] = *(const uint4*)(bp + (size_t)ft * 16 * nsp + kb);
        for (int ks = k0; ks < k1; ++ks) {
            int kn = min(ks + 1, k1 - 1) * 32;
            uint4 na0 = *(const uint4*)(apE + kn);
            uint4 na1 = *(const uint4*)(apP + kn);
            uint4 nb[8];
#pragma unroll
            for (int ft = 0; ft < 8; ++ft)
                nb[ft] = *(const uint4*)(bp + (size_t)ft * 16 * nsp + kn);
            bf16x8 aE = __builtin_bit_cast(bf16x8, ca0);
            bf16x8 aP = __builtin_bit_cast(bf16x8, ca1);
#pragma unroll
            for (int ft = 0; ft < 8; ++ft) {
                bf16x8 bf = __builtin_bit_cast(bf16x8, cb[ft]);
                accE[ft] = __builtin_amdgcn_mfma_f32_16x16x32_bf16(aE, bf, accE[ft], 0, 0, 0);
                accP[ft] = __builtin_amdgcn_mfma_f32_16x16x32_bf16(aP, bf, accP[ft], 0, 0, 0);
            }
            ca0 = na0; ca1 = na1;
#pragma unroll
            for (int ft = 0; ft < 8; ++ft) cb[ft] = nb[ft];
        }
    }
    float* po = part + (size_t)blockIdx.x * 16384;
    int quad = lane >> 4, mr = lane & 15;
#pragma unroll
    for (int ft = 0; ft < 8; ++ft) {
        int col = ft * 16 + mr;
#pragma unroll
        for (int r = 0; r < 4; ++r) {
            po[(size_t)(wv * 16 + quad * 4 + r) * 128 + col] = accE[ft][r];
            po[(size_t)(64 + wv * 16 + quad * 4 + r) * 128 + col] = accP[ft][r];
        }
    }
}

// ---------------- reduce partials: red[i] = sum_p part[p*16384+i] ----------
__global__ __launch_bounds__(256) void k_reduce(
    const float* __restrict__ part, float* __restrict__ red, int gb)
{
    int i = blockIdx.x * 256 + threadIdx.x;   // 0..16383
    float s0 = 0.f, s1 = 0.f, s2 = 0.f, s3 = 0.f;
    int p = 0;
    for (; p + 4 <= gb; p += 4) {
        s0 += part[(size_t)p * 16384 + i];
        s1 += part[(size_t)(p + 1) * 16384 + i];
        s2 += part[(size_t)(p + 2) * 16384 + i];
        s3 += part[(size_t)(p + 3) * 16384 + i];
    }
    for (; p < gb; ++p) s0 += part[(size_t)p * 16384 + i];
    red[i] = (s0 + s1) + (s2 + s3);
}

// ---------------- final: collapsed layer 3 + mean + head, fp32 -------------
__global__ __launch_bounds__(128) void k_final(
    const float* __restrict__ red, const int* __restrict__ batch,
    const float* __restrict__ W3l, const float* __restrict__ b3,
    const float* __restrict__ W3r,
    const float* __restrict__ Wlin, const float* __restrict__ blin,
    float* __restrict__ out, int n)
{
    __shared__ float sE[128], sP[128], tmp[128];
    int g = blockIdx.x;   // 64
    int t = threadIdx.x;  // 128
    sE[t] = red[g * 128 + t];
    sP[t] = red[(64 + g) * 128 + t];

    int lo = 0, hi = n;
    while (lo < hi) { int m = (lo + hi) >> 1; if (batch[m] < g) lo = m + 1; else hi = m; }
    int lb = lo;
    hi = n;
    while (lo < hi) { int m = (lo + hi) >> 1; if (batch[m] < g + 1) lo = m + 1; else hi = m; }
    int cnt = lo - lb;
    float inv = (cnt > 0) ? 1.f / (float)cnt : 0.f;
    __syncthreads();

    float acc = 0.f;
    for (int k = 0; k < 128; ++k)
        acc += sE[k] * W3l[t * 128 + k] + sP[k] * W3r[t * 128 + k];
    tmp[t] = acc * inv + ((cnt > 0) ? b3[t] : 0.f);
    __syncthreads();

    if (t < 64) {
        float o = 0.f;
        for (int k = 0; k < 128; ++k)
            o += tmp[k] * Wlin[t * 128 + k];
        out[g * 64 + t] = o + blin[t];
    }
}

extern "C" void kernel_launch(void* const* d_in, const int* in_sizes, int n_in,
                              void* d_out, int out_size, void* d_ws, size_t ws_size,
                              hipStream_t stream) {
    const float* x     = (const float*)d_in[0];
    const int*   ei    = (const int*)d_in[1];
    const int*   batch = (const int*)d_in[2];
    const float* W1l = (const float*)d_in[3];
    const float* b1l = (const float*)d_in[4];
    const float* W1r = (const float*)d_in[5];
    const float* W2l = (const float*)d_in[6];
    const float* b2l = (const float*)d_in[7];
    const float* W2r = (const float*)d_in[8];
    const float* W3l = (const float*)d_in[9];
    const float* b3l = (const float*)d_in[10];
    const float* W3r = (const float*)d_in[11];
    const float* Wlin = (const float*)d_in[12];
    const float* blin = (const float*)d_in[13];

    const int N = in_sizes[2];       // 50000
    const int E = in_sizes[1] / 2;   // 800000
    const int nb = (N + 127) >> 7;   // 391 buckets
    const int epb = (E + BINB - 1) / BINB;
    const int NSP = ((N + 31) / 32) * 32;        // 50016 (mult of 32)
    const int KSTEPS = NSP / 32;                 // 1563
    const int NCH = (NSP + CH - 1) / CH;         // 7
    const int GB = 128;                          // gsum K-split blocks

    size_t off = 0;
    auto alloc = [&](size_t bytes) {
        void* p = (char*)d_ws + off;
        off += (bytes + 255) & ~(size_t)255;
        return p;
    };
    int* csr_start = (int*)alloc((size_t)(N + 1) * 4);
    int* cnt_mat   = (int*)alloc((size_t)nb * BINB * 4);
    int* rowloc    = (int*)alloc((size_t)nb * BINB * 4);
    int* btot      = (int*)alloc((size_t)NBMAX * 4);
    int* bbase     = (int*)alloc((size_t)NBMAX * 4);
    int* gestart   = (int*)alloc(256 + 64);
    unsigned short* csr_src = (unsigned short*)alloc((size_t)E * 2);
    unsigned*       binned  = (unsigned*)alloc((size_t)E * 4);
    unsigned short* x_bf = (unsigned short*)alloc((size_t)N * 128 * 2 + 65536);
    unsigned short* hA   = (unsigned short*)alloc((size_t)N * 128 * 2 + 65536);
    unsigned char*  x8   = (unsigned char*)alloc((size_t)N * 128);
    unsigned char*  h1_8 = (unsigned char*)alloc((size_t)N * 128);
    unsigned short* h2Tb = (unsigned short*)alloc((size_t)128 * NSP * 2);
    unsigned short* cntb = (unsigned short*)alloc((size_t)128 * NSP * 2);
    unsigned short* Whi  = (unsigned short*)alloc(2 * 128 * 256 * 2);
    float*          part = (float*)alloc((size_t)GB * 16384 * 4);
    float*          red  = (float*)alloc((size_t)16384 * 4);
    (void)ws_size;

    // --- CSR build + casts (no memsets anywhere) ---
    int n8 = N * 128 / 8;
    int nxblk = (n8 + 255) / 256;
    k_bincast<<<BINB + nxblk + 256, 256, 0, stream>>>(
        ei, cnt_mat, E, nb, epb,
        x, x_bf, x8, n8, nxblk, W1l, W1r, W2l, W2r, Whi);
    k_mrowscan<<<nb, 256, 0, stream>>>(cnt_mat, rowloc, btot);
    k_scan2b<<<1, 256, 0, stream>>>(btot, bbase, nb, csr_start + N);
    k_binscatter<<<BINB, 256, 0, stream>>>(ei, rowloc, bbase, binned, E, nb, epb);
    k_fillfine2<<<nb, 256, 0, stream>>>(binned, bbase, batch, csr_start, csr_src,
                                        gestart, E, nb, N);
    // count + indicator table from sorted CSR (LDS-local, no global atomics)
    k_hist<<<128 * NCH, 256, 0, stream>>>(csr_src, gestart, batch, cntb, N, NSP, NCH);

    int lay_grid  = (N + 15) / 16;    // 3125
    int lay2_grid = NSP / 16;         // 3126 (pad block zero-fills h2Tb tail)

    // Layer 1: fused gather(x fp8) + GEMM -> h1 frags (relu) + h1 fp8 rows
    k_layer<<<lay_grid, 256, 0, stream>>>(x8, csr_start, csr_src, x_bf,
                                          Whi, b1l, hA, h1_8, h2Tb, N, NSP, 0);
    // Layer 2: fused gather(h1 fp8) + GEMM -> bf16 h2T only
    k_layer<<<lay2_grid, 256, 0, stream>>>(h1_8, csr_start, csr_src, hA,
                                           Whi + 32768, b2l, hA, h1_8, h2Tb, N, NSP, 1);
    // gsumE+gsumP as one 128x128xNSP MFMA GEMM -> per-block partials
    k_gsum<<<GB, 256, 0, stream>>>(cntb, h2Tb, part, NSP, KSTEPS, GB);
    // coalesced partial reduction
    k_reduce<<<64, 256, 0, stream>>>(part, red, GB);

    // Head: (gsumE@W3l + gsumP@W3r)/cnt + b3 -> @Wlin + blin
    k_final<<<64, 128, 0, stream>>>(red, batch, W3l, b3l, W3r,
                                    Wlin, blin, (float*)d_out, N);
}